// Round 1
// baseline (78.689 us; speedup 1.0000x reference)
//
#include <hip/hip_runtime.h>

// Problem constants (fixed by setup_inputs): depth (16,1,512,512) fp32, W (8,8) fp32.
// Output (16,3,512,512) fp32.
//
// Math reduction: out[b,c,h,w] = sign(depth[b,0,h,w]) * W[0,1+c] / ||W[0,1:4]||
// (0 where depth==0). The Euler scan factor and spectral norm cancel in the
// final normalization. Pure bandwidth kernel: 16.8MB read + 50.3MB write.

constexpr int HW   = 512 * 512;   // 262144 (divisible by 4 -> float4 never crosses image)
constexpr int BATCH = 16;
constexpr int NPIX = BATCH * HW;  // 4194304

__global__ __launch_bounds__(256)
void scene_normal_kernel(const float* __restrict__ depth,
                         const float* __restrict__ Wm,
                         float* __restrict__ out)
{
    // W row-major 8x8: row 0, cols 1..3
    const float w0 = Wm[1], w1 = Wm[2], w2 = Wm[3];
    const float inv = rsqrtf(w0 * w0 + w1 * w1 + w2 * w2);
    const float n0 = w0 * inv, n1 = w1 * inv, n2 = w2 * inv;

    const int idx4 = blockIdx.x * blockDim.x + threadIdx.x;  // index of float4 group
    const int p = idx4 * 4;                                  // pixel index
    if (p >= NPIX) return;

    const float4 x4 = *reinterpret_cast<const float4*>(depth + p);
    float xs[4] = {x4.x, x4.y, x4.z, x4.w};
    float s[4];
#pragma unroll
    for (int i = 0; i < 4; ++i)
        s[i] = (xs[i] > 0.0f) ? 1.0f : ((xs[i] < 0.0f) ? -1.0f : 0.0f);

    const int b = p / HW;          // image index
    const int q = p - b * HW;      // pixel within image (multiple of 4)
    float* obase = out + (size_t)b * 3 * HW + q;

    float4 o;
    o.x = s[0] * n0; o.y = s[1] * n0; o.z = s[2] * n0; o.w = s[3] * n0;
    *reinterpret_cast<float4*>(obase) = o;
    o.x = s[0] * n1; o.y = s[1] * n1; o.z = s[2] * n1; o.w = s[3] * n1;
    *reinterpret_cast<float4*>(obase + HW) = o;
    o.x = s[0] * n2; o.y = s[1] * n2; o.z = s[2] * n2; o.w = s[3] * n2;
    *reinterpret_cast<float4*>(obase + 2 * HW) = o;
}

extern "C" void kernel_launch(void* const* d_in, const int* in_sizes, int n_in,
                              void* d_out, int out_size, void* d_ws, size_t ws_size,
                              hipStream_t stream)
{
    const float* depth = (const float*)d_in[0];  // 16*1*512*512 fp32
    const float* Wm    = (const float*)d_in[1];  // 8*8 fp32
    float* out = (float*)d_out;                  // 16*3*512*512 fp32

    const int groups = NPIX / 4;                 // 1,048,576 float4 groups
    const int block = 256;
    const int grid = (groups + block - 1) / block;  // 4096 blocks
    scene_normal_kernel<<<grid, block, 0, stream>>>(depth, Wm, out);
}